// Round 6
// baseline (1311.204 us; speedup 1.0000x reference)
//
#include <hip/hip_runtime.h>
#include <math.h>

#define BATCH 8
#define SSIZE 1048576   // 128*128*64
#define KT 16

// ---------------- zero kernel (graph-capture-safe G clear) ----------------
__global__ void zero_kernel(float* __restrict__ p, int n) {
    int i = blockIdx.x * blockDim.x + threadIdx.x;
    if (i < n) p[i] = 0.0f;
}

// =====================================================================
// gram_sym (modes 0/1, d=128): G = G^T (no conjugation), so compute 3 of
// 4 64x64 tiles: tile 0=(0,0) 1=(0,64) 2=(64,64); tile 1 mirrors into
// (64,0) via dual atomics. LDS double-buffer + register prefetch (bare
// launch_bounds: VGPR cap caused the R2/R3 spills, not prefetch).
// 4x4 complex acc/thread, float4 staging, conflict-free float4 frag reads.
// u(b,i,k): off = b*SSIZE + i*SI + (k>>KL2)*SKH + (k & ((1<<KL2)-1))
// =====================================================================
template<int SI_, int KL2_, int SKH_>
__global__ __launch_bounds__(256)
void gram_sym_kernel(const float* __restrict__ srcR, const float* __restrict__ srcI,
                     float* __restrict__ G, int kPerBlock)
{
    const int tile = blockIdx.x;             // 0,1,2
    const int it = (tile == 2) ? 64 : 0;
    const int jt = (tile == 0) ? 0 : 64;
    const bool diag = (it == jt);
    const int b  = blockIdx.y;
    const int kbase0 = blockIdx.z * kPerBlock;

    const int t  = threadIdx.x;
    const int ti = t & 15, tj = t >> 4;

    __shared__ float2 As[2][KT][66];
    __shared__ float2 Bs[2][KT][66];

    float accr[4][4] = {{0.f}}, acci[4][4] = {{0.f}};

    const size_t boff = (size_t)b * SSIZE;
    const int nT = kPerBlock >> 4;

    const int kq = t & 3;       // k float4 index
    const int r0 = t >> 2;      // row 0..63

    float4 aR, aI, bR, bI;

    #define GADDR(ii, k) (boff + (size_t)(ii) * SI_ + \
        (size_t)((k) >> KL2_) * SKH_ + (size_t)((k) & ((1 << KL2_) - 1)))

    {   // prologue: tile 0 -> buffer 0
        const int kb = kbase0;
        const size_t offA = GADDR(it + r0, kb + kq * 4);
        const size_t offB = GADDR(jt + r0, kb + kq * 4);
        aR = *(const float4*)(srcR + offA);
        aI = *(const float4*)(srcI + offA);
        bR = *(const float4*)(srcR + offB);
        bI = *(const float4*)(srcI + offB);
        As[0][kq * 4 + 0][r0] = make_float2(aR.x, aI.x);
        As[0][kq * 4 + 1][r0] = make_float2(aR.y, aI.y);
        As[0][kq * 4 + 2][r0] = make_float2(aR.z, aI.z);
        As[0][kq * 4 + 3][r0] = make_float2(aR.w, aI.w);
        Bs[0][kq * 4 + 0][r0] = make_float2(bR.x, bI.x);
        Bs[0][kq * 4 + 1][r0] = make_float2(bR.y, bI.y);
        Bs[0][kq * 4 + 2][r0] = make_float2(bR.z, bI.z);
        Bs[0][kq * 4 + 3][r0] = make_float2(bR.w, bI.w);
    }
    __syncthreads();

    for (int kt = 0; kt < nT; kt++) {
        const int cur = kt & 1, nxt = cur ^ 1;
        const bool have_next = (kt + 1 < nT);
        if (have_next) {
            const int kb = kbase0 + (kt + 1) * KT;
            const size_t offA = GADDR(it + r0, kb + kq * 4);
            const size_t offB = GADDR(jt + r0, kb + kq * 4);
            aR = *(const float4*)(srcR + offA);
            aI = *(const float4*)(srcI + offA);
            bR = *(const float4*)(srcR + offB);
            bI = *(const float4*)(srcI + offB);
        }
        #pragma unroll
        for (int kk = 0; kk < KT; kk++) {
            float4 a4[2], b4[2];
            #pragma unroll
            for (int q = 0; q < 2; q++) a4[q] = *(const float4*)&As[cur][kk][2 * ti + 32 * q];
            #pragma unroll
            for (int q = 0; q < 2; q++) b4[q] = *(const float4*)&Bs[cur][kk][2 * tj + 32 * q];
            #pragma unroll
            for (int r = 0; r < 4; r++) {
                const float ax = (r & 1) ? a4[r >> 1].z : a4[r >> 1].x;
                const float ay = (r & 1) ? a4[r >> 1].w : a4[r >> 1].y;
                #pragma unroll
                for (int c = 0; c < 4; c++) {
                    const float bx = (c & 1) ? b4[c >> 1].z : b4[c >> 1].x;
                    const float by = (c & 1) ? b4[c >> 1].w : b4[c >> 1].y;
                    accr[r][c] = fmaf(ax,  bx, accr[r][c]);
                    accr[r][c] = fmaf(-ay, by, accr[r][c]);
                    acci[r][c] = fmaf(ax,  by, acci[r][c]);
                    acci[r][c] = fmaf(ay,  bx, acci[r][c]);
                }
            }
        }
        if (have_next) {
            As[nxt][kq * 4 + 0][r0] = make_float2(aR.x, aI.x);
            As[nxt][kq * 4 + 1][r0] = make_float2(aR.y, aI.y);
            As[nxt][kq * 4 + 2][r0] = make_float2(aR.z, aI.z);
            As[nxt][kq * 4 + 3][r0] = make_float2(aR.w, aI.w);
            Bs[nxt][kq * 4 + 0][r0] = make_float2(bR.x, bI.x);
            Bs[nxt][kq * 4 + 1][r0] = make_float2(bR.y, bI.y);
            Bs[nxt][kq * 4 + 2][r0] = make_float2(bR.z, bI.z);
            Bs[nxt][kq * 4 + 3][r0] = make_float2(bR.w, bI.w);
        }
        __syncthreads();
    }
    #undef GADDR

    float* Gb = G + (size_t)b * 128 * 128 * 2;
    #pragma unroll
    for (int r = 0; r < 4; r++) {
        const int i = it + 2 * ti + (r & 1) + 32 * (r >> 1);
        #pragma unroll
        for (int c = 0; c < 4; c++) {
            const int j = jt + 2 * tj + (c & 1) + 32 * (c >> 1);
            atomicAdd(&Gb[(i * 128 + j) * 2 + 0], accr[r][c]);
            atomicAdd(&Gb[(i * 128 + j) * 2 + 1], acci[r][c]);
            if (!diag) {  // mirror: G[j][i] = G[i][j]
                atomicAdd(&Gb[(j * 128 + i) * 2 + 0], accr[r][c]);
                atomicAdd(&Gb[(j * 128 + i) * 2 + 1], acci[r][c]);
            }
        }
    }
}

// =====================================================================
// gram64 (mode 2, d=64): round-5 proven version (single-buffer, bare bounds)
// =====================================================================
__global__ __launch_bounds__(256)
void gram64_kernel(const float* __restrict__ srcR, const float* __restrict__ srcI,
                   float* __restrict__ G, int kPerBlock)
{
    const int b      = blockIdx.x;
    const int kbase0 = blockIdx.y * kPerBlock;
    const int t  = threadIdx.x;
    const int ti = t & 15, tj = t >> 4;

    __shared__ float2 As[32][66];

    float accr[4][4] = {{0.f}}, acci[4][4] = {{0.f}};

    const size_t boff = (size_t)b * SSIZE;
    const int nT = kPerBlock >> 5;

    const int ii4 = (t & 15) * 4;
    const int kk0 = t >> 4;

    #define GADDR64(ii, k) (boff + (size_t)(ii) + \
        (size_t)((k) & 127) * 64 + (size_t)((k) >> 7) * 8192)

    for (int kt = 0; kt < nT; kt++) {
        const int kb = kbase0 + kt * 32;
        #pragma unroll
        for (int m = 0; m < 2; m++) {
            const int kk = kk0 + 16 * m;
            const size_t off = GADDR64(ii4, kb + kk);
            const float4 pR = *(const float4*)(srcR + off);
            const float4 pI = *(const float4*)(srcI + off);
            *(float4*)&As[kk][ii4]     = make_float4(pR.x, pI.x, pR.y, pI.y);
            *(float4*)&As[kk][ii4 + 2] = make_float4(pR.z, pI.z, pR.w, pI.w);
        }
        __syncthreads();

        #pragma unroll
        for (int kk = 0; kk < 32; kk++) {
            float4 a4[2], b4[2];
            #pragma unroll
            for (int q = 0; q < 2; q++) a4[q] = *(const float4*)&As[kk][2 * ti + 32 * q];
            #pragma unroll
            for (int q = 0; q < 2; q++) b4[q] = *(const float4*)&As[kk][2 * tj + 32 * q];
            #pragma unroll
            for (int r = 0; r < 4; r++) {
                const float ax = (r & 1) ? a4[r >> 1].z : a4[r >> 1].x;
                const float ay = (r & 1) ? a4[r >> 1].w : a4[r >> 1].y;
                #pragma unroll
                for (int c = 0; c < 4; c++) {
                    const float bx = (c & 1) ? b4[c >> 1].z : b4[c >> 1].x;
                    const float by = (c & 1) ? b4[c >> 1].w : b4[c >> 1].y;
                    accr[r][c] = fmaf(ax,  bx, accr[r][c]);
                    accr[r][c] = fmaf(-ay, by, accr[r][c]);
                    acci[r][c] = fmaf(ax,  by, acci[r][c]);
                    acci[r][c] = fmaf(ay,  bx, acci[r][c]);
                }
            }
        }
        __syncthreads();
    }
    #undef GADDR64

    float* Gb = G + (size_t)b * 64 * 64 * 2;
    #pragma unroll
    for (int r = 0; r < 4; r++) {
        const int i = 2 * ti + (r & 1) + 32 * (r >> 1);
        #pragma unroll
        for (int c = 0; c < 4; c++) {
            const int j = 2 * tj + (c & 1) + 32 * (c >> 1);
            atomicAdd(&Gb[(i * 64 + j) * 2 + 0], accr[r][c]);
            atomicAdd(&Gb[(i * 64 + j) * 2 + 1], acci[r][c]);
        }
    }
}

// ---------------- score/softmax/phase -> routing matrix M ----------------
__global__ __launch_bounds__(128)
void score_kernel(const float* __restrict__ G,
                  const float* __restrict__ Wre, const float* __restrict__ Wim,
                  const float* __restrict__ log_tau,
                  float2* __restrict__ Mout, int d)
{
    const int b = blockIdx.y;
    const int i = blockIdx.x;
    const int j = threadIdx.x;

    const float2* Gb = (const float2*)G + (size_t)b * d * d;

    float sre = 0.f, sim = 0.f;
    for (int l = 0; l < d; l++) {
        float wr = Wre[i * d + l];
        float wi = Wim[i * d + l];
        float2 g = Gb[l * d + j];
        sre = fmaf(wr, g.x, sre);
        sre = fmaf(-wi, g.y, sre);
        sim = fmaf(wr, g.y, sim);
        sim = fmaf(wi, g.x, sim);
    }

    float mag = sqrtf(sre * sre + sim * sim);
    float tau = fmaxf(expf(log_tau[0]), 1e-8f);
    float scale = tau * sqrtf((float)SSIZE / (float)d);
    float mval = mag / scale;

    __shared__ float red[128];
    red[j] = mval;
    __syncthreads();
    for (int s = d >> 1; s > 0; s >>= 1) {
        if (j < s) red[j] = fmaxf(red[j], red[j + s]);
        __syncthreads();
    }
    float mx = red[0];
    __syncthreads();
    float e = expf(mval - mx);
    red[j] = e;
    __syncthreads();
    for (int s = d >> 1; s > 0; s >>= 1) {
        if (j < s) red[j] += red[j + s];
        __syncthreads();
    }
    float routing = e / red[0];

    float safe = fmaxf(mag, 1e-8f);
    float pre, pim;
    if (mag > 1e-8f) { pre = sre / safe; pim = sim / safe; }
    else             { pre = 1.f;       pim = 0.f; }

    Mout[(size_t)b * d * d + i * d + j] = make_float2(routing * pre, routing * pim);
}

// =====================================================================
// mix128 (modes 0/1, d=128): dst(b,i,k) = sum_j M[b,i,j]*u(b,j,k).
// Tile 64 i x 64 k; j-loop 8x16 with LDS dbuf + reg prefetch; float4
// staging; conflict-free float4 fragment reads; 4x4 complex acc.
// =====================================================================
template<int SI_, int KL2_, int SKH_>
__global__ __launch_bounds__(256)
void mix128_kernel(const float* __restrict__ srcR, const float* __restrict__ srcI,
                   const float2* __restrict__ M,
                   float* __restrict__ dstR, float* __restrict__ dstI)
{
    const int kb0 = blockIdx.x << 6;   // 64-wide k tile (aligned to KLO)
    const int it  = blockIdx.y << 6;   // 64-wide i tile
    const int b   = blockIdx.z;

    const int t  = threadIdx.x;
    const int ti = t & 15;   // i groups
    const int tj = t >> 4;   // k groups

    __shared__ float2 Ms[2][KT][66];   // [buf][jj][ii]
    __shared__ float2 Us[2][KT][66];   // [buf][jj][kk]

    float accr[4][4] = {{0.f}}, acci[4][4] = {{0.f}};

    const size_t boff = (size_t)b * SSIZE;
    const float2* Mb  = M + (size_t)b * 128 * 128;

    #define GADDR(jj, k) (boff + (size_t)(jj) * SI_ + \
        (size_t)((k) >> KL2_) * SKH_ + (size_t)((k) & ((1 << KL2_) - 1)))

    // staging maps
    const int mi  = t >> 2;      // [0,64) i row for M
    const int mjq = t & 3;       // j quad for M
    const int ujj = t >> 4;      // [0,16) j row for U
    const int ukq = t & 15;      // k float4 index for U

    float4 mf0, mf1, uR, uI;

    {   // prologue: jb = 0 -> buffer 0
        const float2* mp = &Mb[(size_t)(it + mi) * 128 + mjq * 4];
        mf0 = *(const float4*)mp;
        mf1 = *(const float4*)(mp + 2);
        const size_t off = GADDR(ujj, kb0 + ukq * 4);
        uR = *(const float4*)(srcR + off);
        uI = *(const float4*)(srcI + off);
        Ms[0][mjq * 4 + 0][mi] = make_float2(mf0.x, mf0.y);
        Ms[0][mjq * 4 + 1][mi] = make_float2(mf0.z, mf0.w);
        Ms[0][mjq * 4 + 2][mi] = make_float2(mf1.x, mf1.y);
        Ms[0][mjq * 4 + 3][mi] = make_float2(mf1.z, mf1.w);
        Us[0][ujj][ukq * 4 + 0] = make_float2(uR.x, uI.x);
        Us[0][ujj][ukq * 4 + 1] = make_float2(uR.y, uI.y);
        Us[0][ujj][ukq * 4 + 2] = make_float2(uR.z, uI.z);
        Us[0][ujj][ukq * 4 + 3] = make_float2(uR.w, uI.w);
    }
    __syncthreads();

    for (int jt = 0; jt < 8; jt++) {
        const int cur = jt & 1, nxt = cur ^ 1;
        const bool have_next = (jt + 1 < 8);
        if (have_next) {
            const int jb = (jt + 1) * KT;
            const float2* mp = &Mb[(size_t)(it + mi) * 128 + jb + mjq * 4];
            mf0 = *(const float4*)mp;
            mf1 = *(const float4*)(mp + 2);
            const size_t off = GADDR(jb + ujj, kb0 + ukq * 4);
            uR = *(const float4*)(srcR + off);
            uI = *(const float4*)(srcI + off);
        }
        #pragma unroll
        for (int jj = 0; jj < KT; jj++) {
            float4 m4[2], u4[2];
            #pragma unroll
            for (int q = 0; q < 2; q++) m4[q] = *(const float4*)&Ms[cur][jj][2 * ti + 32 * q];
            #pragma unroll
            for (int q = 0; q < 2; q++) u4[q] = *(const float4*)&Us[cur][jj][2 * tj + 32 * q];
            #pragma unroll
            for (int r = 0; r < 4; r++) {
                const float mx = (r & 1) ? m4[r >> 1].z : m4[r >> 1].x;
                const float my = (r & 1) ? m4[r >> 1].w : m4[r >> 1].y;
                #pragma unroll
                for (int c = 0; c < 4; c++) {
                    const float ux = (c & 1) ? u4[c >> 1].z : u4[c >> 1].x;
                    const float uy = (c & 1) ? u4[c >> 1].w : u4[c >> 1].y;
                    accr[r][c] = fmaf(mx,  ux, accr[r][c]);
                    accr[r][c] = fmaf(-my, uy, accr[r][c]);
                    acci[r][c] = fmaf(mx,  uy, acci[r][c]);
                    acci[r][c] = fmaf(my,  ux, acci[r][c]);
                }
            }
        }
        if (have_next) {
            Ms[nxt][mjq * 4 + 0][mi] = make_float2(mf0.x, mf0.y);
            Ms[nxt][mjq * 4 + 1][mi] = make_float2(mf0.z, mf0.w);
            Ms[nxt][mjq * 4 + 2][mi] = make_float2(mf1.x, mf1.y);
            Ms[nxt][mjq * 4 + 3][mi] = make_float2(mf1.z, mf1.w);
            Us[nxt][ujj][ukq * 4 + 0] = make_float2(uR.x, uI.x);
            Us[nxt][ujj][ukq * 4 + 1] = make_float2(uR.y, uI.y);
            Us[nxt][ujj][ukq * 4 + 2] = make_float2(uR.z, uI.z);
            Us[nxt][ujj][ukq * 4 + 3] = make_float2(uR.w, uI.w);
        }
        __syncthreads();
    }

    // epilogue: float2 stores along k
    #pragma unroll
    for (int r = 0; r < 4; r++) {
        const int i = it + 2 * ti + (r & 1) + 32 * (r >> 1);
        #pragma unroll
        for (int p = 0; p < 2; p++) {
            const int k = kb0 + 2 * tj + 32 * p;
            const size_t o2 = boff + (size_t)i * SI_ +
                (size_t)(k >> KL2_) * SKH_ + (size_t)(k & ((1 << KL2_) - 1));
            *(float2*)(dstR + o2) = make_float2(accr[r][2 * p], accr[r][2 * p + 1]);
            *(float2*)(dstI + o2) = make_float2(acci[r][2 * p], acci[r][2 * p + 1]);
        }
    }
    #undef GADDR
}

// =====================================================================
// mix64 (mode 2, d=64): u(b,j,k) = boff + j + (k&127)*64 + (k>>7)*8192;
// j (=state dim) is contiguous. Tile: all 64 i x 64 k; j-loop 4x16 dbuf.
// =====================================================================
__global__ __launch_bounds__(256)
void mix64_kernel(const float* __restrict__ srcR, const float* __restrict__ srcI,
                  const float2* __restrict__ M,
                  float* __restrict__ dstR, float* __restrict__ dstI)
{
    const int kb0 = blockIdx.x << 6;   // 64-wide k tile (aligned: kb0%64==0)
    const int b   = blockIdx.y;

    const int t  = threadIdx.x;
    const int ti = t & 15;   // i groups
    const int tj = t >> 4;   // k groups

    __shared__ float2 Ms[2][KT][66];   // [buf][jj][ii]
    __shared__ float2 Us[2][KT][66];   // [buf][jj][kk]

    float accr[4][4] = {{0.f}}, acci[4][4] = {{0.f}};

    const size_t boff = (size_t)b * SSIZE;
    const float2* Mb  = M + (size_t)b * 64 * 64;
    const size_t koff = (size_t)(kb0 & 127) * 64 + (size_t)(kb0 >> 7) * 8192;

    // staging maps
    const int mi  = t >> 2;      // [0,64) i row for M
    const int mjq = t & 3;       // j quad for M
    const int ukk = t >> 2;      // [0,64) k for U
    const int ujq = t & 3;       // j quad for U

    float4 mf0, mf1, uR, uI;

    {   // prologue: jb = 0
        const float2* mp = &Mb[(size_t)mi * 64 + mjq * 4];
        mf0 = *(const float4*)mp;
        mf1 = *(const float4*)(mp + 2);
        const size_t off = boff + (size_t)(ujq * 4) + koff + (size_t)ukk * 64;
        uR = *(const float4*)(srcR + off);
        uI = *(const float4*)(srcI + off);
        Ms[0][mjq * 4 + 0][mi] = make_float2(mf0.x, mf0.y);
        Ms[0][mjq * 4 + 1][mi] = make_float2(mf0.z, mf0.w);
        Ms[0][mjq * 4 + 2][mi] = make_float2(mf1.x, mf1.y);
        Ms[0][mjq * 4 + 3][mi] = make_float2(mf1.z, mf1.w);
        Us[0][ujq * 4 + 0][ukk] = make_float2(uR.x, uI.x);
        Us[0][ujq * 4 + 1][ukk] = make_float2(uR.y, uI.y);
        Us[0][ujq * 4 + 2][ukk] = make_float2(uR.z, uI.z);
        Us[0][ujq * 4 + 3][ukk] = make_float2(uR.w, uI.w);
    }
    __syncthreads();

    for (int jt = 0; jt < 4; jt++) {
        const int cur = jt & 1, nxt = cur ^ 1;
        const bool have_next = (jt + 1 < 4);
        if (have_next) {
            const int jb = (jt + 1) * KT;
            const float2* mp = &Mb[(size_t)mi * 64 + jb + mjq * 4];
            mf0 = *(const float4*)mp;
            mf1 = *(const float4*)(mp + 2);
            const size_t off = boff + (size_t)(jb + ujq * 4) + koff + (size_t)ukk * 64;
            uR = *(const float4*)(srcR + off);
            uI = *(const float4*)(srcI + off);
        }
        #pragma unroll
        for (int jj = 0; jj < KT; jj++) {
            float4 m4[2], u4[2];
            #pragma unroll
            for (int q = 0; q < 2; q++) m4[q] = *(const float4*)&Ms[cur][jj][2 * ti + 32 * q];
            #pragma unroll
            for (int q = 0; q < 2; q++) u4[q] = *(const float4*)&Us[cur][jj][2 * tj + 32 * q];
            #pragma unroll
            for (int r = 0; r < 4; r++) {
                const float mx = (r & 1) ? m4[r >> 1].z : m4[r >> 1].x;
                const float my = (r & 1) ? m4[r >> 1].w : m4[r >> 1].y;
                #pragma unroll
                for (int c = 0; c < 4; c++) {
                    const float ux = (c & 1) ? u4[c >> 1].z : u4[c >> 1].x;
                    const float uy = (c & 1) ? u4[c >> 1].w : u4[c >> 1].y;
                    accr[r][c] = fmaf(mx,  ux, accr[r][c]);
                    accr[r][c] = fmaf(-my, uy, accr[r][c]);
                    acci[r][c] = fmaf(mx,  uy, acci[r][c]);
                    acci[r][c] = fmaf(my,  ux, acci[r][c]);
                }
            }
        }
        if (have_next) {
            Ms[nxt][mjq * 4 + 0][mi] = make_float2(mf0.x, mf0.y);
            Ms[nxt][mjq * 4 + 1][mi] = make_float2(mf0.z, mf0.w);
            Ms[nxt][mjq * 4 + 2][mi] = make_float2(mf1.x, mf1.y);
            Ms[nxt][mjq * 4 + 3][mi] = make_float2(mf1.z, mf1.w);
            Us[nxt][ujq * 4 + 0][ukk] = make_float2(uR.x, uI.x);
            Us[nxt][ujq * 4 + 1][ukk] = make_float2(uR.y, uI.y);
            Us[nxt][ujq * 4 + 2][ukk] = make_float2(uR.z, uI.z);
            Us[nxt][ujq * 4 + 3][ukk] = make_float2(uR.w, uI.w);
        }
        __syncthreads();
    }

    // epilogue: float2 stores along i (i contiguous in dst)
    #pragma unroll
    for (int c = 0; c < 4; c++) {
        const int k = kb0 + 2 * tj + (c & 1) + 32 * (c >> 1);
        const size_t kbase = boff + (size_t)(k & 127) * 64 + (size_t)(k >> 7) * 8192;
        #pragma unroll
        for (int p = 0; p < 2; p++) {
            const int i = 2 * ti + 32 * p;   // rows r=2p (i) and r=2p+1 (i+1)
            *(float2*)(dstR + kbase + i) = make_float2(accr[2 * p][c], accr[2 * p + 1][c]);
            *(float2*)(dstI + kbase + i) = make_float2(acci[2 * p][c], acci[2 * p + 1][c]);
        }
    }
}

extern "C" void kernel_launch(void* const* d_in, const int* in_sizes, int n_in,
                              void* d_out, int out_size, void* d_ws, size_t ws_size,
                              hipStream_t stream)
{
    const float* xr  = (const float*)d_in[0];
    const float* xi  = (const float*)d_in[1];
    const float* w0r = (const float*)d_in[2];
    const float* w0i = (const float*)d_in[3];
    const float* w1r = (const float*)d_in[4];
    const float* w1i = (const float*)d_in[5];
    const float* w2r = (const float*)d_in[6];
    const float* w2i = (const float*)d_in[7];
    const float* lt  = (const float*)d_in[8];

    float* outR = (float*)d_out;
    float* outI = outR + (size_t)BATCH * SSIZE;

    float*  wsR = (float*)d_ws;
    float*  wsI = wsR + (size_t)BATCH * SSIZE;
    float*  Gf  = wsI + (size_t)BATCH * SSIZE;
    float2* Mf  = (float2*)(Gf + (size_t)BATCH * 128 * 128 * 2);

    const int nG = BATCH * 128 * 128 * 2;

    // ---------------- mode 0: d=128, SI=8192, KL2=13
    zero_kernel<<<dim3((nG + 255) / 256), 256, 0, stream>>>(Gf, nG);
    gram_sym_kernel<8192, 13, 0><<<dim3(3, BATCH, 64), 256, 0, stream>>>(xr, xi, Gf, 128);
    score_kernel<<<dim3(128, BATCH), 128, 0, stream>>>(Gf, w0r, w0i, lt, Mf, 128);
    mix128_kernel<8192, 13, 0><<<dim3(128, 2, BATCH), 256, 0, stream>>>(xr, xi, Mf, outR, outI);

    // ---------------- mode 1: d=128, SI=64, KL2=6, SKH=8192
    zero_kernel<<<dim3((nG + 255) / 256), 256, 0, stream>>>(Gf, nG);
    gram_sym_kernel<64, 6, 8192><<<dim3(3, BATCH, 64), 256, 0, stream>>>(outR, outI, Gf, 128);
    score_kernel<<<dim3(128, BATCH), 128, 0, stream>>>(Gf, w1r, w1i, lt, Mf, 128);
    mix128_kernel<64, 6, 8192><<<dim3(128, 2, BATCH), 256, 0, stream>>>(outR, outI, Mf, wsR, wsI);

    // ---------------- mode 2: d=64, SI=1, k: (k&127)*64 + (k>>7)*8192
    zero_kernel<<<dim3((nG + 255) / 256), 256, 0, stream>>>(Gf, nG);
    gram64_kernel<<<dim3(BATCH, 64), 256, 0, stream>>>(wsR, wsI, Gf, 256);
    score_kernel<<<dim3(64, BATCH), 64, 0, stream>>>(Gf, w2r, w2i, lt, Mf, 64);
    mix64_kernel<<<dim3(256, BATCH), 256, 0, stream>>>(wsR, wsI, Mf, outR, outI);
}

// Round 7
// 1150.224 us; speedup vs baseline: 1.1400x; 1.1400x over previous
//
#include <hip/hip_runtime.h>
#include <math.h>

#define BATCH 8
#define SSIZE 1048576   // 128*128*64
#define KT 16

// ---------------- zero kernel (graph-capture-safe G clear) ----------------
__global__ void zero_kernel(float* __restrict__ p, int n) {
    int i = blockIdx.x * blockDim.x + threadIdx.x;
    if (i < n) p[i] = 0.0f;
}

// =====================================================================
// gram_sym (modes 0/1, d=128): G = G^T (no conj) => 3 of 4 64x64 tiles:
// tile 0=(0,0), 1=(0,64) mirrored into (64,0), 2=(64,64).
// SINGLE-buffer LDS, NO reg prefetch (R2/R3/R6: pipelining always loses
// here — spills or occupancy collapse). gram_v4 body (R5: 267us, VGPR 40).
// Diagonal tiles read B-fragments from As (half the staging).
// u(b,i,k): off = b*SSIZE + i*SI + (k>>KL2)*SKH + (k & ((1<<KL2)-1))
// =====================================================================
template<int SI_, int KL2_, int SKH_>
__global__ __launch_bounds__(256)
void gram_sym_kernel(const float* __restrict__ srcR, const float* __restrict__ srcI,
                     float* __restrict__ G, int kPerBlock)
{
    const int tile = blockIdx.x;             // 0,1,2
    const int it = (tile == 2) ? 64 : 0;
    const int jt = (tile == 0) ? 0 : 64;
    const bool diag = (it == jt);
    const int b  = blockIdx.y;
    const int kbase0 = blockIdx.z * kPerBlock;

    const int t  = threadIdx.x;
    const int ti = t & 15, tj = t >> 4;

    __shared__ float2 As[KT][66];   // [kk][row]; row pitch 528B
    __shared__ float2 Bs[KT][66];

    float accr[4][4] = {{0.f}}, acci[4][4] = {{0.f}};

    const size_t boff = (size_t)b * SSIZE;
    const int nT = kPerBlock >> 4;

    const int kq = t & 3;       // k float4 index
    const int r0 = t >> 2;      // row 0..63

    // B-fragment source: As for diagonal tiles (A==B), Bs otherwise
    float2 (* __restrict__ Bsel)[66] = diag ? As : Bs;

    #define GADDR(ii, k) (boff + (size_t)(ii) * SI_ + \
        (size_t)((k) >> KL2_) * SKH_ + (size_t)((k) & ((1 << KL2_) - 1)))

    for (int kt = 0; kt < nT; kt++) {
        const int kb = kbase0 + kt * KT;
        {
            const size_t offA = GADDR(it + r0, kb + kq * 4);
            const float4 aR = *(const float4*)(srcR + offA);
            const float4 aI = *(const float4*)(srcI + offA);
            As[kq * 4 + 0][r0] = make_float2(aR.x, aI.x);
            As[kq * 4 + 1][r0] = make_float2(aR.y, aI.y);
            As[kq * 4 + 2][r0] = make_float2(aR.z, aI.z);
            As[kq * 4 + 3][r0] = make_float2(aR.w, aI.w);
        }
        if (!diag) {
            const size_t offB = GADDR(jt + r0, kb + kq * 4);
            const float4 bR = *(const float4*)(srcR + offB);
            const float4 bI = *(const float4*)(srcI + offB);
            Bs[kq * 4 + 0][r0] = make_float2(bR.x, bI.x);
            Bs[kq * 4 + 1][r0] = make_float2(bR.y, bI.y);
            Bs[kq * 4 + 2][r0] = make_float2(bR.z, bI.z);
            Bs[kq * 4 + 3][r0] = make_float2(bR.w, bI.w);
        }
        __syncthreads();

        #pragma unroll
        for (int kk = 0; kk < KT; kk++) {
            float4 a4[2], b4[2];
            #pragma unroll
            for (int q = 0; q < 2; q++) a4[q] = *(const float4*)&As[kk][2 * ti + 32 * q];
            #pragma unroll
            for (int q = 0; q < 2; q++) b4[q] = *(const float4*)&Bsel[kk][2 * tj + 32 * q];
            #pragma unroll
            for (int r = 0; r < 4; r++) {
                const float ax = (r & 1) ? a4[r >> 1].z : a4[r >> 1].x;
                const float ay = (r & 1) ? a4[r >> 1].w : a4[r >> 1].y;
                #pragma unroll
                for (int c = 0; c < 4; c++) {
                    const float bx = (c & 1) ? b4[c >> 1].z : b4[c >> 1].x;
                    const float by = (c & 1) ? b4[c >> 1].w : b4[c >> 1].y;
                    accr[r][c] = fmaf(ax,  bx, accr[r][c]);
                    accr[r][c] = fmaf(-ay, by, accr[r][c]);
                    acci[r][c] = fmaf(ax,  by, acci[r][c]);
                    acci[r][c] = fmaf(ay,  bx, acci[r][c]);
                }
            }
        }
        __syncthreads();
    }
    #undef GADDR

    float* Gb = G + (size_t)b * 128 * 128 * 2;
    #pragma unroll
    for (int r = 0; r < 4; r++) {
        const int i = it + 2 * ti + (r & 1) + 32 * (r >> 1);
        #pragma unroll
        for (int c = 0; c < 4; c++) {
            const int j = jt + 2 * tj + (c & 1) + 32 * (c >> 1);
            atomicAdd(&Gb[(i * 128 + j) * 2 + 0], accr[r][c]);
            atomicAdd(&Gb[(i * 128 + j) * 2 + 1], acci[r][c]);
            if (!diag) {  // mirror: G[j][i] = G[i][j]
                atomicAdd(&Gb[(j * 128 + i) * 2 + 0], accr[r][c]);
                atomicAdd(&Gb[(j * 128 + i) * 2 + 1], acci[r][c]);
            }
        }
    }
}

// =====================================================================
// gram64 (mode 2, d=64): round-5 proven version (single-buffer, bare bounds)
// =====================================================================
__global__ __launch_bounds__(256)
void gram64_kernel(const float* __restrict__ srcR, const float* __restrict__ srcI,
                   float* __restrict__ G, int kPerBlock)
{
    const int b      = blockIdx.x;
    const int kbase0 = blockIdx.y * kPerBlock;
    const int t  = threadIdx.x;
    const int ti = t & 15, tj = t >> 4;

    __shared__ float2 As[32][66];

    float accr[4][4] = {{0.f}}, acci[4][4] = {{0.f}};

    const size_t boff = (size_t)b * SSIZE;
    const int nT = kPerBlock >> 5;

    const int ii4 = (t & 15) * 4;
    const int kk0 = t >> 4;

    #define GADDR64(ii, k) (boff + (size_t)(ii) + \
        (size_t)((k) & 127) * 64 + (size_t)((k) >> 7) * 8192)

    for (int kt = 0; kt < nT; kt++) {
        const int kb = kbase0 + kt * 32;
        #pragma unroll
        for (int m = 0; m < 2; m++) {
            const int kk = kk0 + 16 * m;
            const size_t off = GADDR64(ii4, kb + kk);
            const float4 pR = *(const float4*)(srcR + off);
            const float4 pI = *(const float4*)(srcI + off);
            *(float4*)&As[kk][ii4]     = make_float4(pR.x, pI.x, pR.y, pI.y);
            *(float4*)&As[kk][ii4 + 2] = make_float4(pR.z, pI.z, pR.w, pI.w);
        }
        __syncthreads();

        #pragma unroll
        for (int kk = 0; kk < 32; kk++) {
            float4 a4[2], b4[2];
            #pragma unroll
            for (int q = 0; q < 2; q++) a4[q] = *(const float4*)&As[kk][2 * ti + 32 * q];
            #pragma unroll
            for (int q = 0; q < 2; q++) b4[q] = *(const float4*)&As[kk][2 * tj + 32 * q];
            #pragma unroll
            for (int r = 0; r < 4; r++) {
                const float ax = (r & 1) ? a4[r >> 1].z : a4[r >> 1].x;
                const float ay = (r & 1) ? a4[r >> 1].w : a4[r >> 1].y;
                #pragma unroll
                for (int c = 0; c < 4; c++) {
                    const float bx = (c & 1) ? b4[c >> 1].z : b4[c >> 1].x;
                    const float by = (c & 1) ? b4[c >> 1].w : b4[c >> 1].y;
                    accr[r][c] = fmaf(ax,  bx, accr[r][c]);
                    accr[r][c] = fmaf(-ay, by, accr[r][c]);
                    acci[r][c] = fmaf(ax,  by, acci[r][c]);
                    acci[r][c] = fmaf(ay,  bx, acci[r][c]);
                }
            }
        }
        __syncthreads();
    }
    #undef GADDR64

    float* Gb = G + (size_t)b * 64 * 64 * 2;
    #pragma unroll
    for (int r = 0; r < 4; r++) {
        const int i = 2 * ti + (r & 1) + 32 * (r >> 1);
        #pragma unroll
        for (int c = 0; c < 4; c++) {
            const int j = 2 * tj + (c & 1) + 32 * (c >> 1);
            atomicAdd(&Gb[(i * 64 + j) * 2 + 0], accr[r][c]);
            atomicAdd(&Gb[(i * 64 + j) * 2 + 1], acci[r][c]);
        }
    }
}

// ---------------- score/softmax/phase -> routing matrix M ----------------
__global__ __launch_bounds__(128)
void score_kernel(const float* __restrict__ G,
                  const float* __restrict__ Wre, const float* __restrict__ Wim,
                  const float* __restrict__ log_tau,
                  float2* __restrict__ Mout, int d)
{
    const int b = blockIdx.y;
    const int i = blockIdx.x;
    const int j = threadIdx.x;

    const float2* Gb = (const float2*)G + (size_t)b * d * d;

    float sre = 0.f, sim = 0.f;
    for (int l = 0; l < d; l++) {
        float wr = Wre[i * d + l];
        float wi = Wim[i * d + l];
        float2 g = Gb[l * d + j];
        sre = fmaf(wr, g.x, sre);
        sre = fmaf(-wi, g.y, sre);
        sim = fmaf(wr, g.y, sim);
        sim = fmaf(wi, g.x, sim);
    }

    float mag = sqrtf(sre * sre + sim * sim);
    float tau = fmaxf(expf(log_tau[0]), 1e-8f);
    float scale = tau * sqrtf((float)SSIZE / (float)d);
    float mval = mag / scale;

    __shared__ float red[128];
    red[j] = mval;
    __syncthreads();
    for (int s = d >> 1; s > 0; s >>= 1) {
        if (j < s) red[j] = fmaxf(red[j], red[j + s]);
        __syncthreads();
    }
    float mx = red[0];
    __syncthreads();
    float e = expf(mval - mx);
    red[j] = e;
    __syncthreads();
    for (int s = d >> 1; s > 0; s >>= 1) {
        if (j < s) red[j] += red[j + s];
        __syncthreads();
    }
    float routing = e / red[0];

    float safe = fmaxf(mag, 1e-8f);
    float pre, pim;
    if (mag > 1e-8f) { pre = sre / safe; pim = sim / safe; }
    else             { pre = 1.f;       pim = 0.f; }

    Mout[(size_t)b * d * d + i * d + j] = make_float2(routing * pre, routing * pim);
}

// =====================================================================
// mix128 (modes 0/1, d=128): dst(b,i,k) = sum_j M[b,i,j]*u(b,j,k).
// SINGLE-buffer version of R6 mix128 (keep conflict-free float4 frag
// reads + float4 staging; drop dbuf/prefetch per R6 post-mortem).
// Tile 64 i x 64 k; 4x4 complex acc.
// =====================================================================
template<int SI_, int KL2_, int SKH_>
__global__ __launch_bounds__(256)
void mix128_kernel(const float* __restrict__ srcR, const float* __restrict__ srcI,
                   const float2* __restrict__ M,
                   float* __restrict__ dstR, float* __restrict__ dstI)
{
    const int kb0 = blockIdx.x << 6;   // 64-wide k tile (aligned to KLO)
    const int it  = blockIdx.y << 6;   // 64-wide i tile
    const int b   = blockIdx.z;

    const int t  = threadIdx.x;
    const int ti = t & 15;   // i groups
    const int tj = t >> 4;   // k groups

    __shared__ float2 Ms[KT][66];   // [jj][ii]
    __shared__ float2 Us[KT][66];   // [jj][kk]

    float accr[4][4] = {{0.f}}, acci[4][4] = {{0.f}};

    const size_t boff = (size_t)b * SSIZE;
    const float2* Mb  = M + (size_t)b * 128 * 128;

    #define GADDR(jj, k) (boff + (size_t)(jj) * SI_ + \
        (size_t)((k) >> KL2_) * SKH_ + (size_t)((k) & ((1 << KL2_) - 1)))

    // staging maps
    const int mi  = t >> 2;      // [0,64) i row for M
    const int mjq = t & 3;       // j quad for M
    const int ujj = t >> 4;      // [0,16) j row for U
    const int ukq = t & 15;      // k float4 index for U

    for (int jt = 0; jt < 8; jt++) {
        const int jb = jt * KT;
        {
            const float2* mp = &Mb[(size_t)(it + mi) * 128 + jb + mjq * 4];
            const float4 mf0 = *(const float4*)mp;
            const float4 mf1 = *(const float4*)(mp + 2);
            Ms[mjq * 4 + 0][mi] = make_float2(mf0.x, mf0.y);
            Ms[mjq * 4 + 1][mi] = make_float2(mf0.z, mf0.w);
            Ms[mjq * 4 + 2][mi] = make_float2(mf1.x, mf1.y);
            Ms[mjq * 4 + 3][mi] = make_float2(mf1.z, mf1.w);
            const size_t off = GADDR(jb + ujj, kb0 + ukq * 4);
            const float4 uR = *(const float4*)(srcR + off);
            const float4 uI = *(const float4*)(srcI + off);
            Us[ujj][ukq * 4 + 0] = make_float2(uR.x, uI.x);
            Us[ujj][ukq * 4 + 1] = make_float2(uR.y, uI.y);
            Us[ujj][ukq * 4 + 2] = make_float2(uR.z, uI.z);
            Us[ujj][ukq * 4 + 3] = make_float2(uR.w, uI.w);
        }
        __syncthreads();

        #pragma unroll
        for (int jj = 0; jj < KT; jj++) {
            float4 m4[2], u4[2];
            #pragma unroll
            for (int q = 0; q < 2; q++) m4[q] = *(const float4*)&Ms[jj][2 * ti + 32 * q];
            #pragma unroll
            for (int q = 0; q < 2; q++) u4[q] = *(const float4*)&Us[jj][2 * tj + 32 * q];
            #pragma unroll
            for (int r = 0; r < 4; r++) {
                const float mx = (r & 1) ? m4[r >> 1].z : m4[r >> 1].x;
                const float my = (r & 1) ? m4[r >> 1].w : m4[r >> 1].y;
                #pragma unroll
                for (int c = 0; c < 4; c++) {
                    const float ux = (c & 1) ? u4[c >> 1].z : u4[c >> 1].x;
                    const float uy = (c & 1) ? u4[c >> 1].w : u4[c >> 1].y;
                    accr[r][c] = fmaf(mx,  ux, accr[r][c]);
                    accr[r][c] = fmaf(-my, uy, accr[r][c]);
                    acci[r][c] = fmaf(mx,  uy, acci[r][c]);
                    acci[r][c] = fmaf(my,  ux, acci[r][c]);
                }
            }
        }
        __syncthreads();
    }

    // epilogue: float2 stores along k
    #pragma unroll
    for (int r = 0; r < 4; r++) {
        const int i = it + 2 * ti + (r & 1) + 32 * (r >> 1);
        #pragma unroll
        for (int p = 0; p < 2; p++) {
            const int k = kb0 + 2 * tj + 32 * p;
            const size_t o2 = boff + (size_t)i * SI_ +
                (size_t)(k >> KL2_) * SKH_ + (size_t)(k & ((1 << KL2_) - 1));
            *(float2*)(dstR + o2) = make_float2(accr[r][2 * p], accr[r][2 * p + 1]);
            *(float2*)(dstI + o2) = make_float2(acci[r][2 * p], acci[r][2 * p + 1]);
        }
    }
    #undef GADDR
}

// =====================================================================
// mix64 (mode 2, d=64): u(b,j,k) = boff + j + (k&127)*64 + (k>>7)*8192;
// SINGLE-buffer version of R6 mix64. All 64 i x 64 k per block.
// =====================================================================
__global__ __launch_bounds__(256)
void mix64_kernel(const float* __restrict__ srcR, const float* __restrict__ srcI,
                  const float2* __restrict__ M,
                  float* __restrict__ dstR, float* __restrict__ dstI)
{
    const int kb0 = blockIdx.x << 6;   // 64-wide k tile
    const int b   = blockIdx.y;

    const int t  = threadIdx.x;
    const int ti = t & 15;   // i groups
    const int tj = t >> 4;   // k groups

    __shared__ float2 Ms[KT][66];   // [jj][ii]
    __shared__ float2 Us[KT][66];   // [jj][kk]

    float accr[4][4] = {{0.f}}, acci[4][4] = {{0.f}};

    const size_t boff = (size_t)b * SSIZE;
    const float2* Mb  = M + (size_t)b * 64 * 64;
    const size_t koff = (size_t)(kb0 & 127) * 64 + (size_t)(kb0 >> 7) * 8192;

    // staging maps
    const int mi  = t >> 2;      // [0,64) i row for M
    const int mjq = t & 3;       // j quad for M
    const int ukk = t >> 2;      // [0,64) k for U
    const int ujq = t & 3;       // j quad for U

    for (int jt = 0; jt < 4; jt++) {
        const int jb = jt * KT;
        {
            const float2* mp = &Mb[(size_t)mi * 64 + jb + mjq * 4];
            const float4 mf0 = *(const float4*)mp;
            const float4 mf1 = *(const float4*)(mp + 2);
            Ms[mjq * 4 + 0][mi] = make_float2(mf0.x, mf0.y);
            Ms[mjq * 4 + 1][mi] = make_float2(mf0.z, mf0.w);
            Ms[mjq * 4 + 2][mi] = make_float2(mf1.x, mf1.y);
            Ms[mjq * 4 + 3][mi] = make_float2(mf1.z, mf1.w);
            const size_t off = boff + (size_t)(jb + ujq * 4) + koff + (size_t)ukk * 64;
            const float4 uR = *(const float4*)(srcR + off);
            const float4 uI = *(const float4*)(srcI + off);
            Us[ujq * 4 + 0][ukk] = make_float2(uR.x, uI.x);
            Us[ujq * 4 + 1][ukk] = make_float2(uR.y, uI.y);
            Us[ujq * 4 + 2][ukk] = make_float2(uR.z, uI.z);
            Us[ujq * 4 + 3][ukk] = make_float2(uR.w, uI.w);
        }
        __syncthreads();

        #pragma unroll
        for (int jj = 0; jj < KT; jj++) {
            float4 m4[2], u4[2];
            #pragma unroll
            for (int q = 0; q < 2; q++) m4[q] = *(const float4*)&Ms[jj][2 * ti + 32 * q];
            #pragma unroll
            for (int q = 0; q < 2; q++) u4[q] = *(const float4*)&Us[jj][2 * tj + 32 * q];
            #pragma unroll
            for (int r = 0; r < 4; r++) {
                const float mx = (r & 1) ? m4[r >> 1].z : m4[r >> 1].x;
                const float my = (r & 1) ? m4[r >> 1].w : m4[r >> 1].y;
                #pragma unroll
                for (int c = 0; c < 4; c++) {
                    const float ux = (c & 1) ? u4[c >> 1].z : u4[c >> 1].x;
                    const float uy = (c & 1) ? u4[c >> 1].w : u4[c >> 1].y;
                    accr[r][c] = fmaf(mx,  ux, accr[r][c]);
                    accr[r][c] = fmaf(-my, uy, accr[r][c]);
                    acci[r][c] = fmaf(mx,  uy, acci[r][c]);
                    acci[r][c] = fmaf(my,  ux, acci[r][c]);
                }
            }
        }
        __syncthreads();
    }

    // epilogue: float2 stores along i (i contiguous in dst)
    #pragma unroll
    for (int c = 0; c < 4; c++) {
        const int k = kb0 + 2 * tj + (c & 1) + 32 * (c >> 1);
        const size_t kbase = boff + (size_t)(k & 127) * 64 + (size_t)(k >> 7) * 8192;
        #pragma unroll
        for (int p = 0; p < 2; p++) {
            const int i = 2 * ti + 32 * p;
            *(float2*)(dstR + kbase + i) = make_float2(accr[2 * p][c], accr[2 * p + 1][c]);
            *(float2*)(dstI + kbase + i) = make_float2(acci[2 * p][c], acci[2 * p + 1][c]);
        }
    }
}

extern "C" void kernel_launch(void* const* d_in, const int* in_sizes, int n_in,
                              void* d_out, int out_size, void* d_ws, size_t ws_size,
                              hipStream_t stream)
{
    const float* xr  = (const float*)d_in[0];
    const float* xi  = (const float*)d_in[1];
    const float* w0r = (const float*)d_in[2];
    const float* w0i = (const float*)d_in[3];
    const float* w1r = (const float*)d_in[4];
    const float* w1i = (const float*)d_in[5];
    const float* w2r = (const float*)d_in[6];
    const float* w2i = (const float*)d_in[7];
    const float* lt  = (const float*)d_in[8];

    float* outR = (float*)d_out;
    float* outI = outR + (size_t)BATCH * SSIZE;

    float*  wsR = (float*)d_ws;
    float*  wsI = wsR + (size_t)BATCH * SSIZE;
    float*  Gf  = wsI + (size_t)BATCH * SSIZE;
    float2* Mf  = (float2*)(Gf + (size_t)BATCH * 128 * 128 * 2);

    const int nG = BATCH * 128 * 128 * 2;

    // ---------------- mode 0: d=128, SI=8192, KL2=13
    zero_kernel<<<dim3((nG + 255) / 256), 256, 0, stream>>>(Gf, nG);
    gram_sym_kernel<8192, 13, 0><<<dim3(3, BATCH, 64), 256, 0, stream>>>(xr, xi, Gf, 128);
    score_kernel<<<dim3(128, BATCH), 128, 0, stream>>>(Gf, w0r, w0i, lt, Mf, 128);
    mix128_kernel<8192, 13, 0><<<dim3(128, 2, BATCH), 256, 0, stream>>>(xr, xi, Mf, outR, outI);

    // ---------------- mode 1: d=128, SI=64, KL2=6, SKH=8192
    zero_kernel<<<dim3((nG + 255) / 256), 256, 0, stream>>>(Gf, nG);
    gram_sym_kernel<64, 6, 8192><<<dim3(3, BATCH, 64), 256, 0, stream>>>(outR, outI, Gf, 128);
    score_kernel<<<dim3(128, BATCH), 128, 0, stream>>>(Gf, w1r, w1i, lt, Mf, 128);
    mix128_kernel<64, 6, 8192><<<dim3(128, 2, BATCH), 256, 0, stream>>>(outR, outI, Mf, wsR, wsI);

    // ---------------- mode 2: d=64, SI=1, k: (k&127)*64 + (k>>7)*8192
    zero_kernel<<<dim3((nG + 255) / 256), 256, 0, stream>>>(Gf, nG);
    gram64_kernel<<<dim3(BATCH, 64), 256, 0, stream>>>(wsR, wsI, Gf, 256);
    score_kernel<<<dim3(64, BATCH), 64, 0, stream>>>(Gf, w2r, w2i, lt, Mf, 64);
    mix64_kernel<<<dim3(256, BATCH), 256, 0, stream>>>(wsR, wsI, Mf, outR, outI);
}